// Round 15
// baseline (1027.132 us; speedup 1.0000x reference)
//
#include <hip/hip_runtime.h>
#include <math.h>

// Problem constants
#define ST 64      // sequence length T
#define NBAT 64    // batch B
#define ED 256     // embedding dim E
#define HD 512     // hidden dim H
#define G4 2048    // 4*H
#define VO 32000   // vocab
#define NWORK 64               // recurrence blocks
#define NLOG 192               // logits worker blocks
#define NTILES (VO / 128)      // 250 vocab n-tiles
#define SLOT32 (NBAT * HD / 2) // u32s per h slot (64 KB)
#define NTHR 576               // 8 compute waves + 1 poller wave

typedef unsigned int u32;
typedef unsigned long long u64;
typedef __bf16 bf16;
typedef bf16 bf16x8 __attribute__((ext_vector_type(8)));
typedef float f32x4 __attribute__((ext_vector_type(4)));

__device__ __forceinline__ float sigm(float x) { return 1.f / (1.f + expf(-x)); }

// ---------------- prep kernels ----------------

__global__ void k_lengths(const int* __restrict__ toks, int* __restrict__ len) {
  int b = threadIdx.x;
  if (b < NBAT) {
    int n = 0;
    for (int t = 0; t < ST; ++t) n += (toks[b * ST + t] != 0) ? 1 : 0;
    len[b] = n;
  }
}

// one launch: 4 weight casts + 2 bias sums (segment-dispatched, memory-bound)
#define SEG0 (G4 * ED)              // eWih
#define SEG1 (SEG0 + G4 * HD)       // eWhh
#define SEG2 (SEG1 + G4 * ED)       // dWih
#define SEG3 (SEG2 + G4 * HD)       // dWhh
#define SEG4 (SEG3 + G4)            // bsumE
#define SEG5 (SEG4 + G4)            // bsumD
__global__ void k_prep(const float* __restrict__ eWih, const float* __restrict__ eWhh,
                       const float* __restrict__ dWih, const float* __restrict__ dWhh,
                       const float* __restrict__ ebih, const float* __restrict__ ebhh,
                       const float* __restrict__ dbih, const float* __restrict__ dbhh,
                       bf16* __restrict__ WihEb, bf16* __restrict__ WhhEb,
                       bf16* __restrict__ WihDb, bf16* __restrict__ WhhDb,
                       float* __restrict__ bsumE, float* __restrict__ bsumD) {
  int i = blockIdx.x * blockDim.x + threadIdx.x;
  if (i < SEG0)      WihEb[i] = (bf16)eWih[i];
  else if (i < SEG1) WhhEb[i - SEG0] = (bf16)eWhh[i - SEG0];
  else if (i < SEG2) WihDb[i - SEG1] = (bf16)dWih[i - SEG1];
  else if (i < SEG3) WhhDb[i - SEG2] = (bf16)dWhh[i - SEG2];
  else if (i < SEG4) { int j = i - SEG3; bsumE[j] = ebih[j] + ebhh[j]; }
  else if (i < SEG5) { int j = i - SEG4; bsumD[j] = dbih[j] + dbhh[j]; }
}

// encX[t][b][e] = emb[toks[b][t]][e]; decX[t][b][e] = emb[t==0 ? 1 : toks[b][t-1]][e]
__global__ void k_gather(const int* __restrict__ toks, const float* __restrict__ emb,
                         bf16* __restrict__ encX, bf16* __restrict__ decX) {
  int i = blockIdx.x * blockDim.x + threadIdx.x;
  if (i >= ST * NBAT * ED) return;
  int e = i % ED;
  int tb = i / ED;
  int b = tb % NBAT;
  int t = tb / NBAT;
  int te = toks[b * ST + t];
  encX[i] = (bf16)emb[te * ED + e];
  int td = (t == 0) ? 1 : toks[b * ST + t - 1];
  decX[i] = (bf16)emb[td * ED + e];
}

// ---------------- fused persistent kernel ----------------
//
// 256 blocks x 576 threads (9 waves), 1 block/CU (LDS-forced).
// Blocks 0..63: recurrence. Blocks 64..255: logits workers.
//
// r15 recurrence: CHUNK-GATED h-MFMA with a DEDICATED POLLER WAVE.
//   Wave 8 polls the 64 dense flags (64 fabric pollers chip-wide, the
//   r7/r10-proven population) and publishes a 16-bit group mask to LDS
//   (bit kk = producers 4kk..4kk+3 have fired step). The 8 compute waves
//   gate each h-chunk kk on mask bit kk (LDS spin, staggered start), so
//   loads+MFMAs of early-fired chunks overlap the straggler window
//   instead of serializing after full detection. Mask double-buffered by
//   step parity; wave8 clears the other-parity word each step (safe: its
//   readers passed barrier1 of the previous step). Split-fire from r14
//   unchanged (waves 0-3 cell+drain+count, wave 3 fires; waves 4-7 sail).
//
// r15 workers: leftover tiles 192..249 split 3 ways to kill the tail:
//   lid<116: secondary-first -- tile 192+lid/2, t-range [0,22) or [22,44)
//     runs IN-STEP early in decode, then the primary tile restages and
//     catches up in-step (backlog clears in the remaining decode window).
//   lid in [116,174): primary, then tile 192+(lid-116) t in [44,64) as a
//     short (~21 us) post-pass.  lid>=174: primary only.
__global__ __launch_bounds__(NTHR, 1) void k_fused(
    const bf16* __restrict__ encX, const bf16* __restrict__ decX,
    const bf16* __restrict__ WihE, const bf16* __restrict__ WhhE,
    const bf16* __restrict__ WihD, const bf16* __restrict__ WhhD,
    const float* __restrict__ bsumE, const float* __restrict__ bsumD,
    const int* __restrict__ len,
    const float* __restrict__ linW, const float* __restrict__ linb,
    float* __restrict__ out,
    u32* __restrict__ hx32,    // [2*ST+1][NWORK][NBAT][8/2] per-step h slots
    u32* flags,                // [64] dense worker progress
    u32* decgo)                // [1] block0 broadcast of confirmed step
{
  __shared__ __align__(16) char smem[133632];

  const int tid  = threadIdx.x;
  const int lane = tid & 63;
  const int wid  = tid >> 6;       // 0..8
  const int blk  = blockIdx.x;
  const int r16  = lane & 15;
  const int kh   = lane >> 4;
  const int kc   = kh * 8;

  if (blk < NWORK) {
    // ================= recurrence block =================
    auto Wr  = (bf16(*)[HD + 8])smem;                 // 32 x 520 bf16 -> 33280
    auto Wx  = (bf16(*)[ED + 8])(smem + 33280);       // 32 x 264 bf16 -> +16896
    auto gl  = (float(*)[64][33])(smem + 50176);      // 2 x 64 x 33 f32 -> +16896
    u32* gmask = (u32*)(smem + 67072);                // [2] per-parity group masks
    u32* dcnt  = (u32*)(smem + 67080);                // monotonic wave-done count

    const int wm   = wid & 3;        // m-fragment (batch rows 16*wm..)
    const int wn   = (wid >> 2) & 1; // n-fragment (cols 16*wn..), 0..1
    const int u0   = blk * 8;
    const int hi   = kh;             // 1KB sub-offset inside a 4KB chunk
    const int arow = 16 * wm + r16;  // batch row for A-frags
    const int brow = 16 * wn + r16;  // LDS row for B-frags

    const int eb   = (tid & 255) >> 2;   // 0..63
    const int j2   = (tid & 3) * 2;
    const int elen = len[eb];

    if (tid == 0) { gmask[0] = 0; gmask[1] = 0; *dcnt = 0; }
    u32 hp = 0;

    for (int phase = 0; phase < 2; ++phase) {
      const bf16* Wih  = phase ? WihD : WihE;
      const bf16* Whh  = phase ? WhhD : WhhE;
      const float* bsum = phase ? bsumD : bsumE;
      const bf16* Xall = phase ? decX : encX;

      for (int idx = tid; idx < 32 * HD; idx += NTHR) {
        int n = idx >> 9, k = idx & (HD - 1);
        Wr[n][k] = Whh[((n >> 3) * HD + u0 + (n & 7)) * HD + k];
      }
      for (int idx = tid; idx < 32 * ED; idx += NTHR) {
        int n = idx >> 8, k = idx & (ED - 1);
        Wx[n][k] = Wih[((n >> 3) * HD + u0 + (n & 7)) * ED + k];
      }
      const float bi0 = bsum[0 * HD + u0 + j2], bi1 = bsum[0 * HD + u0 + j2 + 1];
      const float bf0 = bsum[1 * HD + u0 + j2], bf1 = bsum[1 * HD + u0 + j2 + 1];
      const float bg0 = bsum[2 * HD + u0 + j2], bg1 = bsum[2 * HD + u0 + j2 + 1];
      const float bo0 = bsum[3 * HD + u0 + j2], bo1 = bsum[3 * HD + u0 + j2 + 1];
      float c0 = 0.f, c1 = 0.f;
      __syncthreads();  // weights + gmask/dcnt published

      for (int t = 0; t < ST; ++t) {
        const int step = phase * ST + t;
        const int par  = step & 1;

        if (wid == 8) {
          // ---------- poller wave ----------
          if (lane == 0)
            __hip_atomic_store(&gmask[par ^ 1], 0u, __ATOMIC_RELAXED,
                               __HIP_MEMORY_SCOPE_WORKGROUP);
          if (step > 0) {
            for (;;) {
              u32 f = __hip_atomic_load(&flags[lane], __ATOMIC_RELAXED,
                                        __HIP_MEMORY_SCOPE_AGENT);
              u64 bal = __ballot((int)(f >= (u32)step));
              u32 m = 0;
              #pragma unroll
              for (int g = 0; g < 16; ++g)
                if (((bal >> (4 * g)) & 0xFull) == 0xFull) m |= (1u << g);
              if (lane == 0)
                __hip_atomic_store(&gmask[par], m, __ATOMIC_RELAXED,
                                   __HIP_MEMORY_SCOPE_WORKGROUP);
              if (bal == ~0ull) break;
              __builtin_amdgcn_s_sleep(1);
            }
            if (blk == 0 && lane == 0)
              __hip_atomic_store(decgo, (u32)step, __ATOMIC_RELAXED,
                                 __HIP_MEMORY_SCOPE_AGENT);
          }
          __syncthreads();  // barrier1
        } else {
          // ---------- compute waves ----------
          u32* hxout = hx32 + (size_t)(step + 1) * SLOT32 + blk * 256;
          const bf16* xin = Xall + t * (NBAT * ED);

          // x-part first (no dependence on peers)
          f32x4 acc1 = {0.f, 0.f, 0.f, 0.f};
          #pragma unroll
          for (int kk = 0; kk < ED / 32; ++kk) {
            bf16x8 av = *(const bf16x8*)(xin + arow * ED + kk * 32 + kc);
            bf16x8 bv = *(const bf16x8*)(&Wx[brow][kk * 32 + kc]);
            acc1 = __builtin_amdgcn_mfma_f32_16x16x32_bf16(av, bv, acc1, 0, 0, 0);
          }

          // h-part: 16 chunks, each gated on its group-mask bit
          const bf16* hbase = (const bf16*)(hx32 + (size_t)step * SLOT32);
          const bf16* hptr  = hbase + (size_t)hi * 512 + arow * 8;
          f32x4 accA = {0.f, 0.f, 0.f, 0.f};
          f32x4 accB = {0.f, 0.f, 0.f, 0.f};
          #pragma unroll
          for (int kkx = 0; kkx < 16; ++kkx) {
            int kk = (kkx + 2 * wid) & 15;  // staggered start across waves
            if (step > 0) {
              u32 m = __hip_atomic_load(&gmask[par], __ATOMIC_RELAXED,
                                        __HIP_MEMORY_SCOPE_WORKGROUP);
              while (!((m >> kk) & 1u)) {
                __builtin_amdgcn_s_sleep(1);
                m = __hip_atomic_load(&gmask[par], __ATOMIC_RELAXED,
                                      __HIP_MEMORY_SCOPE_WORKGROUP);
              }
              __builtin_amdgcn_fence(__ATOMIC_ACQUIRE, "wavefront");
              __builtin_amdgcn_sched_barrier(0);
            }
            bf16x8 a = *(const bf16x8*)(hptr + (size_t)kk * 2048);
            bf16x8 b = *(const bf16x8*)(&Wr[brow][kk * 32 + kc]);
            if (kkx & 1) accB = __builtin_amdgcn_mfma_f32_16x16x32_bf16(a, b, accB, 0, 0, 0);
            else         accA = __builtin_amdgcn_mfma_f32_16x16x32_bf16(a, b, accA, 0, 0, 0);
          }
          #pragma unroll
          for (int r = 0; r < 4; ++r)
            gl[par][16 * wm + kh * 4 + r][16 * wn + r16] = accA[r] + accB[r] + acc1[r];
          __syncthreads();  // barrier1: gl[par] ready

          // cell + split-fire: waves 0-3; waves 4-7 go straight to t+1
          if (tid < 256) {
            float gi0 = gl[par][eb][j2]      + bi0, gi1 = gl[par][eb][j2 + 1]  + bi1;
            float gf0 = gl[par][eb][8 + j2]  + bf0, gf1 = gl[par][eb][9 + j2]  + bf1;
            float gg0 = gl[par][eb][16 + j2] + bg0, gg1 = gl[par][eb][17 + j2] + bg1;
            float go0 = gl[par][eb][24 + j2] + bo0, go1 = gl[par][eb][25 + j2] + bo1;
            bool upd = (phase == 1) || (t < elen);
            float cn0 = sigm(gf0) * c0 + sigm(gi0) * tanhf(gg0);
            float cn1 = sigm(gf1) * c1 + sigm(gi1) * tanhf(gg1);
            float hn0 = sigm(go0) * tanhf(cn0);
            float hn1 = sigm(go1) * tanhf(cn1);
            if (upd) {
              c0 = cn0; c1 = cn1;
              union { u32 u; bf16 h[2]; } pk;
              pk.h[0] = (bf16)hn0; pk.h[1] = (bf16)hn1;
              hp = pk.u;
            }
            __hip_atomic_store(&hxout[tid], hp, __ATOMIC_RELAXED,
                               __HIP_MEMORY_SCOPE_AGENT);
            asm volatile("s_waitcnt vmcnt(0)" ::: "memory");  // own stores acked
            __builtin_amdgcn_sched_barrier(0);
            if (lane == 0)
              __hip_atomic_fetch_add(dcnt, 1u, __ATOMIC_RELAXED,
                                     __HIP_MEMORY_SCOPE_WORKGROUP);
            if (wid == 3) {  // firer: spin LDS counter, then fire
              u32 c = __hip_atomic_load(dcnt, __ATOMIC_RELAXED,
                                        __HIP_MEMORY_SCOPE_WORKGROUP);
              while (c < 4u * (u32)(step + 1)) {
                __builtin_amdgcn_s_sleep(1);
                c = __hip_atomic_load(dcnt, __ATOMIC_RELAXED,
                                      __HIP_MEMORY_SCOPE_WORKGROUP);
              }
              if (lane == 0)
                __hip_atomic_store(&flags[blk], (u32)(step + 1), __ATOMIC_RELAXED,
                                   __HIP_MEMORY_SCOPE_AGENT);
            }
          }
        }
      }
    }

    // block0 poller: confirm the final fire (flags=128) for the workers
    if (blk == 0 && wid == 8) {
      u32 f = __hip_atomic_load(&flags[lane], __ATOMIC_RELAXED,
                                __HIP_MEMORY_SCOPE_AGENT);
      while (!__all((int)(f >= (u32)(2 * ST)))) {
        __builtin_amdgcn_s_sleep(1);
        f = __hip_atomic_load(&flags[lane], __ATOMIC_RELAXED,
                              __HIP_MEMORY_SCOPE_AGENT);
      }
      if (lane == 0)
        __hip_atomic_store(decgo, (u32)(2 * ST), __ATOMIC_RELAXED,
                           __HIP_MEMORY_SCOPE_AGENT);
    }
  } else {
    // ================= logits worker =================
    auto Bs = (bf16(*)[HD + 8])smem;           // 128 x 520 bf16 (133120 B)
    u32* bgo = (u32*)(smem + 133120);
    const int lid = blk - NWORK;               // 0..191
    const int wm = wid & 3, wn = (wid >> 2) & 1;
    const int arow = 16 * wm + r16;

    if (tid == 0) *bgo = 0;

    auto run_tile = [&](int nt, int tlo, int thi) {
      __syncthreads();  // previous tile fully consumed before restage
      for (int idx = tid; idx < 128 * (HD / 8); idx += NTHR) {
        int n = idx >> 6, k8 = (idx & 63) * 8;
        const float* bsrc = linW + (size_t)(nt * 128 + n) * HD + k8;
        f32x4 x0 = *(const f32x4*)bsrc;
        f32x4 x1 = *(const f32x4*)(bsrc + 4);
        bf16x8 bv;
        #pragma unroll
        for (int e = 0; e < 4; ++e) { bv[e] = (bf16)x0[e]; bv[4 + e] = (bf16)x1[e]; }
        *(bf16x8*)&Bs[n][k8] = bv;
      }
      __syncthreads();
      if (wid >= 8) return;  // poller wave idles in worker blocks

      for (int t = tlo; t < thi; ++t) {
        const u32 target = (u32)(ST + 1 + t);
        if (wid == 0) {
          u32 v = __hip_atomic_load(decgo, __ATOMIC_RELAXED,
                                    __HIP_MEMORY_SCOPE_AGENT);
          while (v < target) {
            __builtin_amdgcn_s_sleep(64);
            v = __hip_atomic_load(decgo, __ATOMIC_RELAXED,
                                  __HIP_MEMORY_SCOPE_AGENT);
          }
          if (lane == 0)
            __hip_atomic_store(bgo, v, __ATOMIC_RELAXED,
                               __HIP_MEMORY_SCOPE_WORKGROUP);
        } else {
          u32 g = __hip_atomic_load(bgo, __ATOMIC_RELAXED,
                                    __HIP_MEMORY_SCOPE_WORKGROUP);
          while (g < target) {
            __builtin_amdgcn_s_sleep(8);
            g = __hip_atomic_load(bgo, __ATOMIC_RELAXED,
                                  __HIP_MEMORY_SCOPE_WORKGROUP);
          }
        }
        __builtin_amdgcn_fence(__ATOMIC_ACQUIRE, "wavefront");
        __builtin_amdgcn_sched_barrier(0);

        // A = h(65+t); chunk order rotated by lid to spread the herd
        const bf16* slotA = (const bf16*)(hx32 + (size_t)target * SLOT32);
        const bf16* aptr  = slotA + (size_t)kh * 512 + arow * 8;
        f32x4 acc[4];
        #pragma unroll
        for (int jj = 0; jj < 4; ++jj) acc[jj] = (f32x4){0.f, 0.f, 0.f, 0.f};
        #pragma unroll
        for (int kk = 0; kk < 16; ++kk) {
          int kks = (kk + lid) & 15;
          bf16x8 av = *(const bf16x8*)(aptr + (size_t)kks * 2048);
          #pragma unroll
          for (int jj = 0; jj < 4; ++jj) {
            bf16x8 bv = *(const bf16x8*)(&Bs[64 * wn + 16 * jj + r16][kks * 32 + kc]);
            acc[jj] = __builtin_amdgcn_mfma_f32_16x16x32_bf16(av, bv, acc[jj], 0, 0, 0);
          }
        }
        #pragma unroll
        for (int jj = 0; jj < 4; ++jj) {
          int col = nt * 128 + 64 * wn + 16 * jj + r16;
          float bias = linb[col];
          #pragma unroll
          for (int r = 0; r < 4; ++r) {
            int b = 16 * wm + kh * 4 + r;
            out[((size_t)b * ST + t) * VO + col] = acc[jj][r] + bias;
          }
        }
      }
    };

    if (lid < 116) {
      // secondary-first (early t-ranges run in-step), then primary catches up
      run_tile(192 + lid / 2, (lid & 1) * 22, (lid & 1) * 22 + 22);
      run_tile(lid, 0, ST);
    } else if (lid < 174) {
      run_tile(lid, 0, ST);
      run_tile(192 + (lid - 116), 44, ST);   // short post-pass (~21 us)
    } else {
      run_tile(lid, 0, ST);
    }
  }
}

// ---------------- host ----------------

extern "C" void kernel_launch(void* const* d_in, const int* in_sizes, int n_in,
                              void* d_out, int out_size, void* d_ws, size_t ws_size,
                              hipStream_t stream) {
  const int*   toks = (const int*)d_in[0];
  const float* emb  = (const float*)d_in[1];
  const float* eWih = (const float*)d_in[2];
  const float* eWhh = (const float*)d_in[3];
  const float* ebih = (const float*)d_in[4];
  const float* ebhh = (const float*)d_in[5];
  const float* dWih = (const float*)d_in[6];
  const float* dWhh = (const float*)d_in[7];
  const float* dbih = (const float*)d_in[8];
  const float* dbhh = (const float*)d_in[9];
  const float* linW = (const float*)d_in[10];
  const float* linb = (const float*)d_in[11];
  float* out = (float*)d_out;

  char* ws = (char*)d_ws;
  size_t off = 0;
  auto alloc = [&](size_t bytes) {
    void* p = ws + off;
    off = (off + bytes + 255) & ~(size_t)255;
    return p;
  };
  bf16* encX  = (bf16*)alloc((size_t)ST * NBAT * ED * 2);
  bf16* decX  = (bf16*)alloc((size_t)ST * NBAT * ED * 2);
  bf16* WihEb = (bf16*)alloc((size_t)G4 * ED * 2);
  bf16* WhhEb = (bf16*)alloc((size_t)G4 * HD * 2);
  bf16* WihDb = (bf16*)alloc((size_t)G4 * ED * 2);
  bf16* WhhDb = (bf16*)alloc((size_t)G4 * HD * 2);
  float* bsumE = (float*)alloc(G4 * 4);
  float* bsumD = (float*)alloc(G4 * 4);
  u32*  hx    = (u32*)alloc((size_t)(2 * ST + 1) * SLOT32 * 4);  // 129 x 64 KB
  int*  len   = (int*)alloc(NBAT * 4);
  u32*  flags = (u32*)alloc(4096);
  u32*  decgo = flags + 64;   // own line (byte 256), inside memset region

  // slot 0 (h(0)=0) + flags/decgo must be clean every launch
  hipMemsetAsync(hx, 0, (size_t)SLOT32 * 4, stream);
  hipMemsetAsync(flags, 0, 4096, stream);

  k_lengths<<<1, 64, 0, stream>>>(toks, len);
  k_prep<<<(SEG5 + 255) / 256, 256, 0, stream>>>(
      eWih, eWhh, dWih, dWhh, ebih, ebhh, dbih, dbhh,
      WihEb, WhhEb, WihDb, WhhDb, bsumE, bsumD);
  k_gather<<<(ST * NBAT * ED + 255) / 256, 256, 0, stream>>>(toks, emb, encX, decX);

  k_fused<<<NWORK + NLOG, NTHR, 0, stream>>>(
      encX, decX, WihEb, WhhEb, WihDb, WhhDb, bsumE, bsumD, len,
      linW, linb, out, hx, flags, decgo);
}

// Round 16
// 621.418 us; speedup vs baseline: 1.6529x; 1.6529x over previous
//
#include <hip/hip_runtime.h>
#include <math.h>

// Problem constants
#define ST 64      // sequence length T
#define NBAT 64    // batch B
#define ED 256     // embedding dim E
#define HD 512     // hidden dim H
#define G4 2048    // 4*H
#define VO 32000   // vocab
#define NWORK 64               // recurrence blocks
#define NLOG 192               // logits worker blocks
#define NTILES (VO / 128)      // 250 vocab n-tiles
#define SLOT32 (NBAT * HD / 2) // u32s per h slot (64 KB)

typedef unsigned int u32;
typedef __bf16 bf16;
typedef bf16 bf16x8 __attribute__((ext_vector_type(8)));
typedef float f32x4 __attribute__((ext_vector_type(4)));

__device__ __forceinline__ float sigm(float x) { return 1.f / (1.f + expf(-x)); }

// ---------------- prep kernels ----------------

__global__ void k_lengths(const int* __restrict__ toks, int* __restrict__ len) {
  int b = threadIdx.x;
  if (b < NBAT) {
    int n = 0;
    for (int t = 0; t < ST; ++t) n += (toks[b * ST + t] != 0) ? 1 : 0;
    len[b] = n;
  }
}

// one launch: 4 weight casts + 2 bias sums (segment-dispatched, memory-bound)
#define SEG0 (G4 * ED)              // eWih
#define SEG1 (SEG0 + G4 * HD)       // eWhh
#define SEG2 (SEG1 + G4 * ED)       // dWih
#define SEG3 (SEG2 + G4 * HD)       // dWhh
#define SEG4 (SEG3 + G4)            // bsumE
#define SEG5 (SEG4 + G4)            // bsumD
__global__ void k_prep(const float* __restrict__ eWih, const float* __restrict__ eWhh,
                       const float* __restrict__ dWih, const float* __restrict__ dWhh,
                       const float* __restrict__ ebih, const float* __restrict__ ebhh,
                       const float* __restrict__ dbih, const float* __restrict__ dbhh,
                       bf16* __restrict__ WihEb, bf16* __restrict__ WhhEb,
                       bf16* __restrict__ WihDb, bf16* __restrict__ WhhDb,
                       float* __restrict__ bsumE, float* __restrict__ bsumD) {
  int i = blockIdx.x * blockDim.x + threadIdx.x;
  if (i < SEG0)      WihEb[i] = (bf16)eWih[i];
  else if (i < SEG1) WhhEb[i - SEG0] = (bf16)eWhh[i - SEG0];
  else if (i < SEG2) WihDb[i - SEG1] = (bf16)dWih[i - SEG1];
  else if (i < SEG3) WhhDb[i - SEG2] = (bf16)dWhh[i - SEG2];
  else if (i < SEG4) { int j = i - SEG3; bsumE[j] = ebih[j] + ebhh[j]; }
  else if (i < SEG5) { int j = i - SEG4; bsumD[j] = dbih[j] + dbhh[j]; }
}

// encX[t][b][e] = emb[toks[b][t]][e]; decX[t][b][e] = emb[t==0 ? 1 : toks[b][t-1]][e]
__global__ void k_gather(const int* __restrict__ toks, const float* __restrict__ emb,
                         bf16* __restrict__ encX, bf16* __restrict__ decX) {
  int i = blockIdx.x * blockDim.x + threadIdx.x;
  if (i >= ST * NBAT * ED) return;
  int e = i % ED;
  int tb = i / ED;
  int b = tb % NBAT;
  int t = tb / NBAT;
  int te = toks[b * ST + t];
  encX[i] = (bf16)emb[te * ED + e];
  int td = (t == 0) ? 1 : toks[b * ST + t - 1];
  decX[i] = (bf16)emb[td * ED + e];
}

// ---------------- fused persistent kernel ----------------
//
// 256 blocks x 512 threads, 1 block/CU. Blocks 0..63: recurrence (r14
// structure -- best measured). Blocks 64..255: logits workers.
//
// Recurrence (r14 split-fire): gl double-buffered by parity; after
// barrier1 each of the 4 h-storing waves independently cells -> bypass
// stores -> drains OWN vmcnt -> bumps LDS counter; wave 3 spins the
// counter and fires flags[blk]. Waves 4-7 sail into step+1's x-MFMA.
// Wait = wave0 polling the 64 dense flags + LDS bounce (64 fabric
// pollers chip-wide). r15's chunk-gating REVERTED: its poller wave only
// exited at full detection before barrier1, so gating bought nothing
// and cost 35% (1014 us).
//
// r16 worker change (tail fix, post-pass only): leftover tiles 192..249
// are split 3-way by t-segment and run AFTER each worker's primary tile:
//   lid<58:       tile 192+lid,        t [0,22)
//   58<=lid<116:  tile 192+(lid-58),   t [22,43)
//   116<=lid<174: tile 192+(lid-116),  t [43,64)
// All segments execute when data is already published (decgo waits pass
// instantly) -> tail ~20 us across 174 blocks instead of ~60 us across
// 58, with ZERO in-step interference (r15's in-step variant regressed).
__global__ __launch_bounds__(512, 2) void k_fused(
    const bf16* __restrict__ encX, const bf16* __restrict__ decX,
    const bf16* __restrict__ WihE, const bf16* __restrict__ WhhE,
    const bf16* __restrict__ WihD, const bf16* __restrict__ WhhD,
    const float* __restrict__ bsumE, const float* __restrict__ bsumD,
    const int* __restrict__ len,
    const float* __restrict__ linW, const float* __restrict__ linb,
    float* __restrict__ out,
    u32* __restrict__ hx32,    // [2*ST+1][NWORK][NBAT][8/2] per-step h slots
    u32* flags,                // [64] dense worker progress
    u32* decgo)                // [1] block0 broadcast of confirmed step
{
  __shared__ __align__(16) char smem[133632];

  const int tid  = threadIdx.x;
  const int lane = tid & 63;
  const int wid  = tid >> 6;
  const int blk  = blockIdx.x;
  const int r16  = lane & 15;
  const int kh   = lane >> 4;
  const int kc   = kh * 8;

  if (blk < NWORK) {
    // ================= recurrence block =================
    auto Wr  = (bf16(*)[HD + 8])smem;                 // 32 x 520 bf16 -> 33280
    auto Wx  = (bf16(*)[ED + 8])(smem + 33280);       // 32 x 264 bf16 -> +16896
    auto gl  = (float(*)[64][33])(smem + 50176);      // 2 x 64 x 33 f32 -> +16896
    u32* go_lds = (u32*)(smem + 67072);
    u32* dcnt   = (u32*)(smem + 67076);               // monotonic wave-done count

    const int wm   = wid & 3;        // m-fragment (batch rows 16*wm..)
    const int wn   = wid >> 2;       // n-fragment (cols 16*wn..), 0..1
    const int u0   = blk * 8;
    const int hi   = kh;             // which 8-chunk of the 32-K slice
    const int arow = 16 * wm + r16;  // batch row for A-frags
    const int brow = 16 * wn + r16;  // LDS row for B-frags

    const int eb   = (tid & 255) >> 2;   // 0..63
    const int j2   = (tid & 3) * 2;
    const int elen = len[eb];

    if (tid == 0) { *go_lds = 0; *dcnt = 0; }
    u32 hp = 0;

    for (int phase = 0; phase < 2; ++phase) {
      const bf16* Wih  = phase ? WihD : WihE;
      const bf16* Whh  = phase ? WhhD : WhhE;
      const float* bsum = phase ? bsumD : bsumE;
      const bf16* Xall = phase ? decX : encX;

      for (int idx = tid; idx < 32 * HD; idx += 512) {
        int n = idx >> 9, k = idx & (HD - 1);
        Wr[n][k] = Whh[((n >> 3) * HD + u0 + (n & 7)) * HD + k];
      }
      for (int idx = tid; idx < 32 * ED; idx += 512) {
        int n = idx >> 8, k = idx & (ED - 1);
        Wx[n][k] = Wih[((n >> 3) * HD + u0 + (n & 7)) * ED + k];
      }
      const float bi0 = bsum[0 * HD + u0 + j2], bi1 = bsum[0 * HD + u0 + j2 + 1];
      const float bf0 = bsum[1 * HD + u0 + j2], bf1 = bsum[1 * HD + u0 + j2 + 1];
      const float bg0 = bsum[2 * HD + u0 + j2], bg1 = bsum[2 * HD + u0 + j2 + 1];
      const float bo0 = bsum[3 * HD + u0 + j2], bo1 = bsum[3 * HD + u0 + j2 + 1];
      float c0 = 0.f, c1 = 0.f;
      __syncthreads();  // weights + go_lds/dcnt published

      for (int t = 0; t < ST; ++t) {
        const int step = phase * ST + t;
        const int par  = step & 1;
        u32* hxout = hx32 + (size_t)(step + 1) * SLOT32 + blk * 256;
        const bf16* xin = Xall + t * (NBAT * ED);

        // x-part first: overlaps peers' fire propagation
        f32x4 acc1 = {0.f, 0.f, 0.f, 0.f};
        #pragma unroll
        for (int kk = 0; kk < ED / 32; ++kk) {
          bf16x8 av = *(const bf16x8*)(xin + arow * ED + kk * 32 + kc);
          bf16x8 bv = *(const bf16x8*)(&Wx[brow][kk * 32 + kc]);
          acc1 = __builtin_amdgcn_mfma_f32_16x16x32_bf16(av, bv, acc1, 0, 0, 0);
        }

        // wait for h(step): wave0 fabric poll + LDS bounce
        if (step > 0) {
          if (wid == 0) {
            u32 f = __hip_atomic_load(&flags[lane], __ATOMIC_RELAXED,
                                      __HIP_MEMORY_SCOPE_AGENT);
            while (!__all((int)(f >= (u32)step))) {
              __builtin_amdgcn_s_sleep(1);
              f = __hip_atomic_load(&flags[lane], __ATOMIC_RELAXED,
                                    __HIP_MEMORY_SCOPE_AGENT);
            }
            if (lane == 0) {
              __hip_atomic_store(go_lds, (u32)step, __ATOMIC_RELAXED,
                                 __HIP_MEMORY_SCOPE_WORKGROUP);
              if (blk == 0)
                __hip_atomic_store(decgo, (u32)step, __ATOMIC_RELAXED,
                                   __HIP_MEMORY_SCOPE_AGENT);
            }
          } else {
            u32 g = __hip_atomic_load(go_lds, __ATOMIC_RELAXED,
                                      __HIP_MEMORY_SCOPE_WORKGROUP);
            while (g < (u32)step) {
              __builtin_amdgcn_s_sleep(1);
              g = __hip_atomic_load(go_lds, __ATOMIC_RELAXED,
                                    __HIP_MEMORY_SCOPE_WORKGROUP);
            }
          }
          __builtin_amdgcn_fence(__ATOMIC_ACQUIRE, "wavefront");
          __builtin_amdgcn_sched_barrier(0);
        }

        // h-part: 16 chunks, plain cached cold-miss loads
        const bf16* hbase = (const bf16*)(hx32 + (size_t)step * SLOT32);
        const bf16* hptr  = hbase + (size_t)hi * 512 + arow * 8;
        f32x4 accA = {0.f, 0.f, 0.f, 0.f};
        f32x4 accB = {0.f, 0.f, 0.f, 0.f};
        #pragma unroll
        for (int kk = 0; kk < 16; kk += 2) {
          bf16x8 a0 = *(const bf16x8*)(hptr + (size_t)kk * 2048);
          bf16x8 a1 = *(const bf16x8*)(hptr + (size_t)(kk + 1) * 2048);
          bf16x8 b0 = *(const bf16x8*)(&Wr[brow][kk * 32 + kc]);
          bf16x8 b1 = *(const bf16x8*)(&Wr[brow][(kk + 1) * 32 + kc]);
          accA = __builtin_amdgcn_mfma_f32_16x16x32_bf16(a0, b0, accA, 0, 0, 0);
          accB = __builtin_amdgcn_mfma_f32_16x16x32_bf16(a1, b1, accB, 0, 0, 0);
        }
        #pragma unroll
        for (int r = 0; r < 4; ++r)
          gl[par][16 * wm + kh * 4 + r][16 * wn + r16] = accA[r] + accB[r] + acc1[r];
        __syncthreads();  // barrier1: gl[par] ready

        // cell + split-fire: waves 0-3 only; waves 4-7 go straight to t+1
        if (tid < 256) {
          float gi0 = gl[par][eb][j2]      + bi0, gi1 = gl[par][eb][j2 + 1]  + bi1;
          float gf0 = gl[par][eb][8 + j2]  + bf0, gf1 = gl[par][eb][9 + j2]  + bf1;
          float gg0 = gl[par][eb][16 + j2] + bg0, gg1 = gl[par][eb][17 + j2] + bg1;
          float go0 = gl[par][eb][24 + j2] + bo0, go1 = gl[par][eb][25 + j2] + bo1;
          bool upd = (phase == 1) || (t < elen);
          float cn0 = sigm(gf0) * c0 + sigm(gi0) * tanhf(gg0);
          float cn1 = sigm(gf1) * c1 + sigm(gi1) * tanhf(gg1);
          float hn0 = sigm(go0) * tanhf(cn0);
          float hn1 = sigm(go1) * tanhf(cn1);
          if (upd) {
            c0 = cn0; c1 = cn1;
            union { u32 u; bf16 h[2]; } pk;
            pk.h[0] = (bf16)hn0; pk.h[1] = (bf16)hn1;
            hp = pk.u;
          }
          __hip_atomic_store(&hxout[tid], hp, __ATOMIC_RELAXED,
                             __HIP_MEMORY_SCOPE_AGENT);
          // drain OWN wave's bypass stores (acks at coherence point)
          asm volatile("s_waitcnt vmcnt(0)" ::: "memory");
          __builtin_amdgcn_sched_barrier(0);
          if (lane == 0)
            __hip_atomic_fetch_add(dcnt, 1u, __ATOMIC_RELAXED,
                                   __HIP_MEMORY_SCOPE_WORKGROUP);
          if (wid == 3) {  // firer wave: spin LDS counter, then fire
            u32 c = __hip_atomic_load(dcnt, __ATOMIC_RELAXED,
                                      __HIP_MEMORY_SCOPE_WORKGROUP);
            while (c < 4u * (u32)(step + 1)) {
              __builtin_amdgcn_s_sleep(1);
              c = __hip_atomic_load(dcnt, __ATOMIC_RELAXED,
                                    __HIP_MEMORY_SCOPE_WORKGROUP);
            }
            if (lane == 0)
              __hip_atomic_store(&flags[blk], (u32)(step + 1), __ATOMIC_RELAXED,
                                 __HIP_MEMORY_SCOPE_AGENT);
          }
        }
      }
    }

    // block0: confirm the final fire (flags=128) for the logits workers
    if (blk == 0 && wid == 0) {
      u32 f = __hip_atomic_load(&flags[lane], __ATOMIC_RELAXED,
                                __HIP_MEMORY_SCOPE_AGENT);
      while (!__all((int)(f >= (u32)(2 * ST)))) {
        __builtin_amdgcn_s_sleep(1);
        f = __hip_atomic_load(&flags[lane], __ATOMIC_RELAXED,
                              __HIP_MEMORY_SCOPE_AGENT);
      }
      if (lane == 0)
        __hip_atomic_store(decgo, (u32)(2 * ST), __ATOMIC_RELAXED,
                           __HIP_MEMORY_SCOPE_AGENT);
    }
  } else {
    // ================= logits worker =================
    auto Bs = (bf16(*)[HD + 8])smem;           // 128 x 520 bf16 (133120 B)
    u32* bgo = (u32*)(smem + 133120);
    const int lid = blk - NWORK;               // 0..191
    const int wm = wid & 3, wn = wid >> 2;
    const int arow = 16 * wm + r16;

    if (tid == 0) *bgo = 0;

    auto run_tile = [&](int nt, int tlo, int thi) {
      __syncthreads();  // previous tile fully consumed before restage
      // stage B from f32 linW with inline bf16 cvt
      for (int idx = tid; idx < 128 * (HD / 8); idx += 512) {
        int n = idx >> 6, k8 = (idx & 63) * 8;
        const float* bsrc = linW + (size_t)(nt * 128 + n) * HD + k8;
        f32x4 x0 = *(const f32x4*)bsrc;
        f32x4 x1 = *(const f32x4*)(bsrc + 4);
        bf16x8 bv;
        #pragma unroll
        for (int e = 0; e < 4; ++e) { bv[e] = (bf16)x0[e]; bv[4 + e] = (bf16)x1[e]; }
        *(bf16x8*)&Bs[n][k8] = bv;
      }
      __syncthreads();

      for (int t = tlo; t < thi; ++t) {
        const u32 target = (u32)(ST + 1 + t);
        if (wid == 0) {
          u32 v = __hip_atomic_load(decgo, __ATOMIC_RELAXED,
                                    __HIP_MEMORY_SCOPE_AGENT);
          while (v < target) {
            __builtin_amdgcn_s_sleep(64);
            v = __hip_atomic_load(decgo, __ATOMIC_RELAXED,
                                  __HIP_MEMORY_SCOPE_AGENT);
          }
          if (lane == 0)
            __hip_atomic_store(bgo, v, __ATOMIC_RELAXED,
                               __HIP_MEMORY_SCOPE_WORKGROUP);
        } else {
          u32 g = __hip_atomic_load(bgo, __ATOMIC_RELAXED,
                                    __HIP_MEMORY_SCOPE_WORKGROUP);
          while (g < target) {
            __builtin_amdgcn_s_sleep(8);
            g = __hip_atomic_load(bgo, __ATOMIC_RELAXED,
                                  __HIP_MEMORY_SCOPE_WORKGROUP);
          }
        }
        __builtin_amdgcn_fence(__ATOMIC_ACQUIRE, "wavefront");
        __builtin_amdgcn_sched_barrier(0);

        // A = h(65+t); chunk order rotated by lid to spread the herd
        const bf16* slotA = (const bf16*)(hx32 + (size_t)target * SLOT32);
        const bf16* aptr  = slotA + (size_t)kh * 512 + arow * 8;
        f32x4 acc[4];
        #pragma unroll
        for (int jj = 0; jj < 4; ++jj) acc[jj] = (f32x4){0.f, 0.f, 0.f, 0.f};
        #pragma unroll
        for (int kk = 0; kk < 16; ++kk) {
          int kks = (kk + lid) & 15;
          bf16x8 av = *(const bf16x8*)(aptr + (size_t)kks * 2048);
          #pragma unroll
          for (int jj = 0; jj < 4; ++jj) {
            bf16x8 bv = *(const bf16x8*)(&Bs[64 * wn + 16 * jj + r16][kks * 32 + kc]);
            acc[jj] = __builtin_amdgcn_mfma_f32_16x16x32_bf16(av, bv, acc[jj], 0, 0, 0);
          }
        }
        #pragma unroll
        for (int jj = 0; jj < 4; ++jj) {
          int col = nt * 128 + 64 * wn + 16 * jj + r16;
          float bias = linb[col];
          #pragma unroll
          for (int r = 0; r < 4; ++r) {
            int b = 16 * wm + kh * 4 + r;
            out[((size_t)b * ST + t) * VO + col] = acc[jj][r] + bias;
          }
        }
      }
    };

    // primary tile (in-step with the decoder)
    run_tile(lid, 0, ST);
    // leftover tiles 192..249: 3-way t-segment split, post-pass
    if (lid < 58)        run_tile(192 + lid, 0, 22);
    else if (lid < 116)  run_tile(192 + (lid - 58), 22, 43);
    else if (lid < 174)  run_tile(192 + (lid - 116), 43, 64);
  }
}

// ---------------- host ----------------

extern "C" void kernel_launch(void* const* d_in, const int* in_sizes, int n_in,
                              void* d_out, int out_size, void* d_ws, size_t ws_size,
                              hipStream_t stream) {
  const int*   toks = (const int*)d_in[0];
  const float* emb  = (const float*)d_in[1];
  const float* eWih = (const float*)d_in[2];
  const float* eWhh = (const float*)d_in[3];
  const float* ebih = (const float*)d_in[4];
  const float* ebhh = (const float*)d_in[5];
  const float* dWih = (const float*)d_in[6];
  const float* dWhh = (const float*)d_in[7];
  const float* dbih = (const float*)d_in[8];
  const float* dbhh = (const float*)d_in[9];
  const float* linW = (const float*)d_in[10];
  const float* linb = (const float*)d_in[11];
  float* out = (float*)d_out;

  char* ws = (char*)d_ws;
  size_t off = 0;
  auto alloc = [&](size_t bytes) {
    void* p = ws + off;
    off = (off + bytes + 255) & ~(size_t)255;
    return p;
  };
  bf16* encX  = (bf16*)alloc((size_t)ST * NBAT * ED * 2);
  bf16* decX  = (bf16*)alloc((size_t)ST * NBAT * ED * 2);
  bf16* WihEb = (bf16*)alloc((size_t)G4 * ED * 2);
  bf16* WhhEb = (bf16*)alloc((size_t)G4 * HD * 2);
  bf16* WihDb = (bf16*)alloc((size_t)G4 * ED * 2);
  bf16* WhhDb = (bf16*)alloc((size_t)G4 * HD * 2);
  float* bsumE = (float*)alloc(G4 * 4);
  float* bsumD = (float*)alloc(G4 * 4);
  u32*  hx    = (u32*)alloc((size_t)(2 * ST + 1) * SLOT32 * 4);  // 129 x 64 KB
  int*  len   = (int*)alloc(NBAT * 4);
  u32*  flags = (u32*)alloc(4096);
  u32*  decgo = flags + 64;   // own line (byte 256), inside memset region

  // slot 0 (h(0)=0) + flags/decgo must be clean every launch
  hipMemsetAsync(hx, 0, (size_t)SLOT32 * 4, stream);
  hipMemsetAsync(flags, 0, 4096, stream);

  k_lengths<<<1, 64, 0, stream>>>(toks, len);
  k_prep<<<(SEG5 + 255) / 256, 256, 0, stream>>>(
      eWih, eWhh, dWih, dWhh, ebih, ebhh, dbih, dbhh,
      WihEb, WhhEb, WihDb, WhhDb, bsumE, bsumD);
  k_gather<<<(ST * NBAT * ED + 255) / 256, 256, 0, stream>>>(toks, emb, encX, decX);

  k_fused<<<NWORK + NLOG, 512, 0, stream>>>(
      encX, decX, WihEb, WhhEb, WihDb, WhhDb, bsumE, bsumD, len,
      linW, linb, out, hx, flags, decgo);
}